// Round 15
// baseline (2421.196 us; speedup 1.0000x reference)
//
#include <hip/hip_runtime.h>

#define SEQ    1024
#define EDIM   1024
#define NHEAD  16
#define DHEAD  64
#define NLAYER 12
#define NTOK   4096   // B*S
#define QKVN   2048   // fused q|kv output width
#define LOG2E  1.44269504088896f

typedef float f32x4  __attribute__((ext_vector_type(4)));
typedef short bf16x8 __attribute__((ext_vector_type(8)));

__device__ __forceinline__ unsigned short f32_to_bf16(float f) {
    union { float f; unsigned u; } v; v.f = f;
    return (unsigned short)((v.u + 0x7fffu + ((v.u >> 16) & 1u)) >> 16);
}
__device__ __forceinline__ float bf16_to_f32(unsigned short u) {
    union { unsigned u; float f; } v; v.u = (unsigned)u << 16;
    return v.f;
}
__device__ __forceinline__ unsigned cvt_pk_bf16(float a, float b) {
    unsigned r;
    asm("v_cvt_pk_bf16_f32 %0, %1, %2" : "=v"(r) : "v"(a), "v"(b));
    return r;   // lo16 = bf16(a), hi16 = bf16(b), RNE (same as f32_to_bf16)
}

__device__ __forceinline__ float gelu_f(float x) {
    // tanh-form gelu; |err| ~3e-4 vs exact erf — below bf16 rounding here (absmax-verified)
    const float y = 0.7978845608028654f * (x + 0.044715f * x * x * x);
    const float e = __expf(-2.f * fabsf(y));
    float th = (1.f - e) / (1.f + e);
    th = (y < 0.f) ? -th : th;
    return 0.5f * x * (1.f + th);
}

__device__ __forceinline__ void gload_lds16(const unsigned short* g, unsigned short* l) {
    __builtin_amdgcn_global_load_lds((const __attribute__((address_space(1))) void*)g,
                                     (__attribute__((address_space(3))) void*)l, 16, 0, 0);
}

#define BARRIER() do { __builtin_amdgcn_s_barrier(); asm volatile("" ::: "memory"); } while (0)

// ---------------- merged one-time prep (64x64 tiles, 16B-burst conflict-free writes) ----------------
// z 0..11:  Wfc layer z     (K=1024,N=4096): bx = n-tile (0..63), by = k-tile (0..15)
// z 12..23: Wproj layer z-12 (K=4096,N=1024): bx = k-tile (0..63), by = n-tile (0..15)
// z 24..35: Wq (bx 0..15) / Wkv (bx 16..31), layer z-24 (K=N=1024), by = k-tile (0..15)
// z 36:     bias concat (bx<12 = layer, by==0)
__device__ __forceinline__ void transpose_body64(
    const float* __restrict__ W, unsigned short* __restrict__ WT,
    int K, int N, int n0, int k0, int t, float (*tile)[65])
{
    #pragma unroll
    for (int i = 0; i < 4; ++i) {
        const int flat = t + i * 256;          // 0..1023
        const int r  = flat >> 4;              // k-row 0..63
        const int c4 = (flat & 15) * 4;        // n-col 0..60
        const float4 v = *reinterpret_cast<const float4*>(
            &W[(size_t)(k0 + r) * N + n0 + c4]);
        tile[r][c4 + 0] = v.x; tile[r][c4 + 1] = v.y;
        tile[r][c4 + 2] = v.z; tile[r][c4 + 3] = v.w;
    }
    __syncthreads();
    // write: thread -> 16B of one WT row; banks = (8c + j + n) & 31 -> 2-way, free
    #pragma unroll
    for (int i = 0; i < 2; ++i) {
        const int n  = (t >> 3) + i * 32;      // 0..63
        const int k8 = (t & 7) * 8;            // 0..56
        bf16x8 o;
        #pragma unroll
        for (int j = 0; j < 8; ++j)
            o[j] = (short)f32_to_bf16(tile[k8 + j][n]);
        *reinterpret_cast<bf16x8*>(&WT[(size_t)(n0 + n) * K + k0 + k8]) = o;
    }
}

__global__ __launch_bounds__(256) void prep_k(
    const float* __restrict__ Wq, const float* __restrict__ Wkv,
    const float* __restrict__ Wfc, const float* __restrict__ Wproj,
    const float* __restrict__ bq, const float* __restrict__ bkv,
    unsigned short* __restrict__ wqkvT, unsigned short* __restrict__ wfcT,
    unsigned short* __restrict__ wpjT, float* __restrict__ bqkv)
{
    __shared__ float tile[64][65];
    const int z = blockIdx.z;
    const int t = threadIdx.x;
    const size_t E2 = (size_t)EDIM * EDIM;       // 1M
    const size_t E8 = (size_t)4 * EDIM * EDIM;   // 4M

    if (z < 12) {
        transpose_body64(Wfc + (size_t)z * E8, wfcT + (size_t)z * E8,
                         EDIM, 4 * EDIM, blockIdx.x * 64, blockIdx.y * 64, t, tile);
    } else if (z < 24) {
        const int l = z - 12;
        transpose_body64(Wproj + (size_t)l * E8, wpjT + (size_t)l * E8,
                         4 * EDIM, EDIM, blockIdx.y * 64, blockIdx.x * 64, t, tile);
    } else if (z < 36) {
        const int l = z - 24;
        if (blockIdx.x < 16) {
            transpose_body64(Wq + (size_t)l * E2, wqkvT + (size_t)l * QKVN * EDIM,
                             EDIM, EDIM, blockIdx.x * 64, blockIdx.y * 64, t, tile);
        } else if (blockIdx.x < 32) {
            transpose_body64(Wkv + (size_t)l * E2, wqkvT + (size_t)l * QKVN * EDIM + E2,
                             EDIM, EDIM, (blockIdx.x - 16) * 64, blockIdx.y * 64, t, tile);
        }
    } else {
        if (blockIdx.y != 0 || blockIdx.x >= NLAYER) return;
        const int l = blockIdx.x;
        #pragma unroll
        for (int i = 0; i < 4; ++i) {
            const int c = t + i * 256;
            bqkv[(size_t)l * QKVN + c]        = bq[(size_t)l * EDIM + c];
            bqkv[(size_t)l * QKVN + EDIM + c] = bkv[(size_t)l * EDIM + c];
        }
    }
}

// ---------------- embedding ----------------
__global__ __launch_bounds__(256) void embed_k(
    const int* __restrict__ x, const float* __restrict__ wte,
    const float* __restrict__ wpe, float* __restrict__ h,
    unsigned short* __restrict__ hb)
{
    const int bs  = blockIdx.x;
    const int s   = bs & (SEQ - 1);
    const int tok = x[bs];
    const int c   = threadIdx.x * 4;
    float4 a = *reinterpret_cast<const float4*>(&wte[(size_t)tok * EDIM + c]);
    const float4 p = *reinterpret_cast<const float4*>(&wpe[(size_t)s * EDIM + c]);
    a.x += p.x; a.y += p.y; a.z += p.z; a.w += p.w;
    *reinterpret_cast<float4*>(&h[(size_t)bs * EDIM + c]) = a;
    ushort4 o;
    o.x = f32_to_bf16(a.x); o.y = f32_to_bf16(a.y);
    o.z = f32_to_bf16(a.z); o.w = f32_to_bf16(a.w);
    *reinterpret_cast<ushort4*>(&hb[(size_t)bs * EDIM + c]) = o;
}

// ---------------- generic LN (final layernorm) ----------------
template<int WF32, int WBF16>
__global__ __launch_bounds__(256) void add_ln_k(
    const float* __restrict__ x1, const float* __restrict__ g,
    const float* __restrict__ b, float* __restrict__ outf,
    unsigned short* __restrict__ outb)
{
    const int row = blockIdx.x;
    const int t   = threadIdx.x;
    const int c   = t * 4;
    const size_t base = (size_t)row * EDIM + c;
    float4 a = *reinterpret_cast<const float4*>(x1 + base);
    float s  = a.x + a.y + a.z + a.w;
    float ss = a.x * a.x + a.y * a.y + a.z * a.z + a.w * a.w;
    #pragma unroll
    for (int o = 32; o > 0; o >>= 1) {
        s  += __shfl_down(s, o);
        ss += __shfl_down(ss, o);
    }
    __shared__ float rs[4], rss[4];
    const int lane = t & 63, wv = t >> 6;
    if (lane == 0) { rs[wv] = s; rss[wv] = ss; }
    __syncthreads();
    s  = rs[0] + rs[1] + rs[2] + rs[3];
    ss = rss[0] + rss[1] + rss[2] + rss[3];
    const float mean = s * (1.f / EDIM);
    const float var  = ss * (1.f / EDIM) - mean * mean;
    const float inv  = rsqrtf(var + 1e-5f);
    const float4 gv = *reinterpret_cast<const float4*>(g + c);
    const float4 bv = *reinterpret_cast<const float4*>(b + c);
    float4 y;
    y.x = (a.x - mean) * inv * gv.x + bv.x;
    y.y = (a.y - mean) * inv * gv.y + bv.y;
    y.z = (a.z - mean) * inv * gv.z + bv.z;
    y.w = (a.w - mean) * inv * gv.w + bv.w;
    if (WF32) *reinterpret_cast<float4*>(outf + base) = y;
    if (WBF16) {
        ushort4 o;
        o.x = f32_to_bf16(y.x); o.y = f32_to_bf16(y.y);
        o.z = f32_to_bf16(y.z); o.w = f32_to_bf16(y.w);
        *reinterpret_cast<ushort4*>(outb + base) = o;
    }
}

// ---------------- ln1: u = LN(h + att_bf16) -> ub bf16 ----------------
__global__ __launch_bounds__(256) void ln1_k(
    const float* __restrict__ h, const unsigned short* __restrict__ attb,
    const float* __restrict__ g, const float* __restrict__ b,
    unsigned short* __restrict__ ub)
{
    const int row = blockIdx.x;
    const int t   = threadIdx.x;
    const int c   = t * 4;
    const size_t base = (size_t)row * EDIM + c;
    float4 a = *reinterpret_cast<const float4*>(h + base);
    const ushort4 av = *reinterpret_cast<const ushort4*>(attb + base);
    a.x += bf16_to_f32(av.x); a.y += bf16_to_f32(av.y);
    a.z += bf16_to_f32(av.z); a.w += bf16_to_f32(av.w);
    float s  = a.x + a.y + a.z + a.w;
    float ss = a.x * a.x + a.y * a.y + a.z * a.z + a.w * a.w;
    #pragma unroll
    for (int o = 32; o > 0; o >>= 1) {
        s  += __shfl_down(s, o);
        ss += __shfl_down(ss, o);
    }
    __shared__ float rs[4], rss[4];
    const int lane = t & 63, wv = t >> 6;
    if (lane == 0) { rs[wv] = s; rss[wv] = ss; }
    __syncthreads();
    s  = rs[0] + rs[1] + rs[2] + rs[3];
    ss = rss[0] + rss[1] + rss[2] + rss[3];
    const float mean = s * (1.f / EDIM);
    const float var  = ss * (1.f / EDIM) - mean * mean;
    const float inv  = rsqrtf(var + 1e-5f);
    const float4 gv = *reinterpret_cast<const float4*>(g + c);
    const float4 bv = *reinterpret_cast<const float4*>(b + c);
    ushort4 o;
    o.x = f32_to_bf16((a.x - mean) * inv * gv.x + bv.x);
    o.y = f32_to_bf16((a.y - mean) * inv * gv.y + bv.y);
    o.z = f32_to_bf16((a.z - mean) * inv * gv.z + bv.z);
    o.w = f32_to_bf16((a.w - mean) * inv * gv.w + bv.w);
    *reinterpret_cast<ushort4*>(ub + base) = o;
}

// ---------------- ln2: h' = LN(p0+p1+p2+p3 + h) -> h f32 + hb bf16 ----------------
__global__ __launch_bounds__(256) void ln2_k(
    const unsigned short* __restrict__ p0, const unsigned short* __restrict__ p1,
    const unsigned short* __restrict__ p2, const unsigned short* __restrict__ p3,
    const float* __restrict__ h, const float* __restrict__ g,
    const float* __restrict__ b, float* __restrict__ hout,
    unsigned short* __restrict__ hbout)
{
    const int row = blockIdx.x;
    const int t   = threadIdx.x;
    const int c   = t * 4;
    const size_t base = (size_t)row * EDIM + c;
    float4 a = *reinterpret_cast<const float4*>(h + base);
    const ushort4 v0 = *reinterpret_cast<const ushort4*>(p0 + base);
    const ushort4 v1 = *reinterpret_cast<const ushort4*>(p1 + base);
    const ushort4 v2 = *reinterpret_cast<const ushort4*>(p2 + base);
    const ushort4 v3 = *reinterpret_cast<const ushort4*>(p3 + base);
    a.x += bf16_to_f32(v0.x) + bf16_to_f32(v1.x) + bf16_to_f32(v2.x) + bf16_to_f32(v3.x);
    a.y += bf16_to_f32(v0.y) + bf16_to_f32(v1.y) + bf16_to_f32(v2.y) + bf16_to_f32(v3.y);
    a.z += bf16_to_f32(v0.z) + bf16_to_f32(v1.z) + bf16_to_f32(v2.z) + bf16_to_f32(v3.z);
    a.w += bf16_to_f32(v0.w) + bf16_to_f32(v1.w) + bf16_to_f32(v2.w) + bf16_to_f32(v3.w);
    float s  = a.x + a.y + a.z + a.w;
    float ss = a.x * a.x + a.y * a.y + a.z * a.z + a.w * a.w;
    #pragma unroll
    for (int o = 32; o > 0; o >>= 1) {
        s  += __shfl_down(s, o);
        ss += __shfl_down(ss, o);
    }
    __shared__ float rs[4], rss[4];
    const int lane = t & 63, wv = t >> 6;
    if (lane == 0) { rs[wv] = s; rss[wv] = ss; }
    __syncthreads();
    s  = rs[0] + rs[1] + rs[2] + rs[3];
    ss = rss[0] + rss[1] + rss[2] + rss[3];
    const float mean = s * (1.f / EDIM);
    const float var  = ss * (1.f / EDIM) - mean * mean;
    const float inv  = rsqrtf(var + 1e-5f);
    const float4 gv = *reinterpret_cast<const float4*>(g + c);
    const float4 bv = *reinterpret_cast<const float4*>(b + c);
    float4 y;
    y.x = (a.x - mean) * inv * gv.x + bv.x;
    y.y = (a.y - mean) * inv * gv.y + bv.y;
    y.z = (a.z - mean) * inv * gv.z + bv.z;
    y.w = (a.w - mean) * inv * gv.w + bv.w;
    *reinterpret_cast<float4*>(hout + base) = y;
    ushort4 o;
    o.x = f32_to_bf16(y.x); o.y = f32_to_bf16(y.y);
    o.z = f32_to_bf16(y.z); o.w = f32_to_bf16(y.w);
    *reinterpret_cast<ushort4*>(hbout + base) = o;
}

// ---------------- GEMM m97 (128^2, used for qkv; QSCALE multiplies cols<EDIM by log2e) ----------------
template<int GELU, int OUTBF16, int QSCALE>
__global__ __launch_bounds__(256) void gemm_bt_k(
    const unsigned short* __restrict__ A,
    const unsigned short* __restrict__ BT,
    const float* __restrict__ bias, void* __restrict__ Cout,
    void* __restrict__ Cout2, int M, int N, int K)
{
    __shared__ unsigned short As[128 * 32];
    __shared__ unsigned short Bs[128 * 32];

    const int t    = threadIdx.x;
    const int lane = t & 63;
    const int wave = t >> 6;
    const int wr   = wave >> 1, wc = wave & 1;
    const int lrow = lane & 15, lgrp = lane >> 4;

    const int nbx = gridDim.x;
    int flat = blockIdx.y * nbx + blockIdx.x;
    const int nwg = nbx * gridDim.y;
    flat = (flat & 7) * (nwg >> 3) + (flat >> 3);
    const int row0 = (flat / nbx) * 128, col0 = (flat % nbx) * 128;

    const int kspan = K / gridDim.z;
    const int koff  = blockIdx.z * kspan;

    const int srow  = lane >> 2;
    const int skoff = (lane & 3) * 8;
    const unsigned short* aP0 = A  + (size_t)(row0 + 32 * wave + srow) * K + skoff;
    const unsigned short* aP1 = aP0 + (size_t)16 * K;
    const unsigned short* bP0 = BT + (size_t)(col0 + 32 * wave + srow) * K + skoff;
    const unsigned short* bP1 = bP0 + (size_t)16 * K;
    unsigned short* aL0 = As + wave * 1024;
    unsigned short* aL1 = As + wave * 1024 + 512;
    unsigned short* bL0 = Bs + wave * 1024;
    unsigned short* bL1 = Bs + wave * 1024 + 512;

    f32x4 acc[4][4];
    #pragma unroll
    for (int i = 0; i < 4; ++i)
        #pragma unroll
        for (int j = 0; j < 4; ++j)
            acc[i][j] = (f32x4){0.f, 0.f, 0.f, 0.f};

    for (int k0 = koff; k0 < koff + kspan; k0 += 32) {
        gload_lds16(aP0 + k0, aL0);
        gload_lds16(aP1 + k0, aL1);
        gload_lds16(bP0 + k0, bL0);
        gload_lds16(bP1 + k0, bL1);
        __syncthreads();

        bf16x8 af[4], bf[4];
        #pragma unroll
        for (int m = 0; m < 4; ++m)
            af[m] = *reinterpret_cast<const bf16x8*>(
                &As[(wr * 64 + m * 16 + lrow) * 32 + lgrp * 8]);
        #pragma unroll
        for (int n = 0; n < 4; ++n)
            bf[n] = *reinterpret_cast<const bf16x8*>(
                &Bs[(wc * 64 + n * 16 + lrow) * 32 + lgrp * 8]);

        #pragma unroll
        for (int n = 0; n < 4; ++n)
            #pragma unroll
            for (int m = 0; m < 4; ++m)
                acc[m][n] = __builtin_amdgcn_mfma_f32_16x16x32_bf16(
                    af[m], bf[n], acc[m][n], 0, 0, 0);
        __syncthreads();
    }

    const int z = blockIdx.z;
    #pragma unroll
    for (int n = 0; n < 4; ++n) {
        const int col = col0 + wc * 64 + n * 16 + lrow;
        const float bv = (z == 0) ? bias[col] : 0.f;
        const float qs = (QSCALE && col < EDIM) ? LOG2E : 1.f;
        #pragma unroll
        for (int m = 0; m < 4; ++m) {
            const int rb = row0 + wr * 64 + m * 16 + lgrp * 4;
            #pragma unroll
            for (int r = 0; r < 4; ++r) {
                float xv = acc[m][n][r] + bv;
                if (GELU) xv = gelu_f(xv);
                if (QSCALE) xv *= qs;
                if (OUTBF16) {
                    ((unsigned short*)Cout)[(size_t)(rb + r) * N + col] = f32_to_bf16(xv);
                } else {
                    float* dst = (z == 0) ? (float*)Cout : (float*)Cout2;
                    dst[(size_t)(rb + r) * N + col] = xv;
                }
            }
        }
    }
}

// ---------------- GEMM 256^2 8-phase; OUT: 0=bf16 C, 2=bf16 4-way split-K partials ----------------
template<int GELU, int OUT>
__global__ __launch_bounds__(512) void gemm256_k(
    const unsigned short* __restrict__ A,
    const unsigned short* __restrict__ BT,
    const float* __restrict__ bias, unsigned short* __restrict__ C,
    void* __restrict__ P0, void* __restrict__ P1,
    void* __restrict__ P2, void* __restrict__ P3,
    int M, int N, int K)
{
    __shared__ unsigned short sh[65536];          // A: [0,32768) B: [32768,65536)
    unsigned short* Asm = sh;
    unsigned short* Bsm = sh + 32768;

    const int tid  = threadIdx.x;
    const int lane = tid & 63;
    const int wave = tid >> 6;
    const int wm   = wave >> 2;
    const int wn   = wave & 3;
    const int lrow = lane & 15, lgrp = lane >> 4;

    const int ntc = N >> 8;
    const int nwg = gridDim.x;
    int flat = (blockIdx.x & 7) * (nwg >> 3) + (blockIdx.x >> 3);
    const int row0 = (flat / ntc) * 256;
    const int col0 = (flat % ntc) * 256;

    const int kspan = K / gridDim.y;
    const int koff  = blockIdx.y * kspan;
    const int NT    = kspan >> 6;

    f32x4 acc[8][4];
    #pragma unroll
    for (int i = 0; i < 8; ++i)
        #pragma unroll
        for (int j = 0; j < 4; ++j)
            acc[i][j] = (f32x4){0.f, 0.f, 0.f, 0.f};

    auto stage_half = [&](const unsigned short* g, unsigned short* l) {
        #pragma unroll
        for (int c = 0; c < 2; ++c) {
            const int d = (tid + c * 512) * 16;
            const int L = d ^ (((d >> 7) & 7) << 4);
            gload_lds16(g + (size_t)(L >> 7) * K + ((L & 127) >> 1), l + (d >> 1));
        }
    };
    auto stageA = [&](int buf, int kt, int h) {
        stage_half(A + (size_t)(row0 + h * 128) * K + koff + kt * 64,
                   Asm + buf * 16384 + h * 8192);
    };
    auto stageB = [&](int buf, int kt, int h) {
        stage_half(BT + (size_t)(col0 + h * 128) * K + koff + kt * 64,
                   Bsm + buf * 16384 + h * 8192);
    };

    auto rdA = [&](int buf, int p, bf16x8 (&af)[2][2]) {
        #pragma unroll
        for (int m = 0; m < 2; ++m)
            #pragma unroll
            for (int ks = 0; ks < 2; ++ks) {
                const int r  = wm * 128 + p * 32 + m * 16 + lrow;
                const int cB = (ks * 64 + lgrp * 16) ^ ((r & 7) << 4);
                af[m][ks] = *reinterpret_cast<const bf16x8*>(
                    &Asm[buf * 16384 + ((r * 128 + cB) >> 1)]);
            }
    };
    auto rdB = [&](int buf, bf16x8 (&bfr)[4][2]) {
        #pragma unroll
        for (int n = 0; n < 4; ++n)
            #pragma unroll
            for (int ks = 0; ks < 2; ++ks) {
                const int r  = wn * 64 + n * 16 + lrow;
                const int cB = (ks * 64 + lgrp * 16) ^ ((r & 7) << 4);
                bfr[n][ks] = *reinterpret_cast<const bf16x8*>(
                    &Bsm[buf * 16384 + ((r * 128 + cB) >> 1)]);
            }
    };
    auto mq = [&](int p, bf16x8 (&af)[2][2], bf16x8 (&bfr)[4][2]) {
        __builtin_amdgcn_s_setprio(1);
        #pragma unroll
        for (int ks = 0; ks < 2; ++ks)
            #pragma unroll
            for (int n = 0; n < 4; ++n)
                #pragma unroll
                for (int m = 0; m < 2; ++m)
                    acc[p * 2 + m][n] = __builtin_amdgcn_mfma_f32_16x16x32_bf16(
                        af[m][ks], bfr[n][ks], acc[p * 2 + m][n], 0, 0, 0);
        __builtin_amdgcn_s_setprio(0);
    };

    stageA(0, 0, 0); stageA(0, 0, 1);
    stageB(0, 0, 0); stageB(0, 0, 1);
    stageA(1, 1, 0); stageA(1, 1, 1);
    stageB(1, 1, 0); stageB(1, 1, 1);
    asm volatile("s_waitcnt vmcnt(8)" ::: "memory");
    BARRIER();

    for (int t = 0; t < NT; t += 2) {
        bf16x8 bfr[4][2], af[2][2];
        // ---- K-tile t (buf 0)
        rdB(0, bfr); rdA(0, 0, af);
        if (t > 0) { stageA(1, t + 1, 0); stageA(1, t + 1, 1); }
        BARRIER(); mq(0, af, bfr); BARRIER();
        rdA(0, 1, af);
        if (t + 2 < NT) stageB(0, t + 2, 0);
        BARRIER(); mq(1, af, bfr); BARRIER();
        rdA(0, 2, af);
        if (t + 2 < NT) stageB(0, t + 2, 1);
        BARRIER(); mq(2, af, bfr); BARRIER();
        rdA(0, 3, af);
        BARRIER(); mq(3, af, bfr);
        if (t + 2 < NT) { asm volatile("s_waitcnt vmcnt(4)" ::: "memory"); }
        else            { asm volatile("s_waitcnt vmcnt(0)" ::: "memory"); }
        BARRIER();
        // ---- K-tile t+1 (buf 1)
        rdB(1, bfr); rdA(1, 0, af);
        if (t + 2 < NT) stageA(0, t + 2, 0);
        BARRIER(); mq(0, af, bfr); BARRIER();
        rdA(1, 1, af);
        if (t + 2 < NT) stageA(0, t + 2, 1);
        if (t + 3 < NT) stageB(1, t + 3, 0);
        BARRIER(); mq(1, af, bfr); BARRIER();
        rdA(1, 2, af);
        if (t + 3 < NT) stageB(1, t + 3, 1);
        BARRIER(); mq(2, af, bfr); BARRIER();
        rdA(1, 3, af);
        BARRIER(); mq(3, af, bfr);
        if (t + 2 < NT) { asm volatile("s_waitcnt vmcnt(4)" ::: "memory"); }
        BARRIER();
    }

    const int z = blockIdx.y;
    #pragma unroll
    for (int n = 0; n < 4; ++n) {
        const int col = col0 + wn * 64 + n * 16 + lrow;
        const float bv = (z == 0) ? bias[col] : 0.f;
        #pragma unroll
        for (int mf = 0; mf < 8; ++mf) {
            const int rb = row0 + wm * 128 + mf * 16 + lgrp * 4;
            #pragma unroll
            for (int r = 0; r < 4; ++r) {
                float xv = acc[mf][n][r] + bv;
                if (GELU) xv = gelu_f(xv);
                if (OUT == 0) {
                    C[(size_t)(rb + r) * N + col] = f32_to_bf16(xv);
                } else {
                    unsigned short* dst = (unsigned short*)(
                        (z == 0) ? P0 : (z == 1) ? P1 : (z == 2) ? P2 : P3);
                    dst[(size_t)(rb + r) * N + col] = f32_to_bf16(xv);
                }
            }
        }
    }
}

// ---------------- flash attention: 8 waves, 256 q-rows, KVBLK=128, exp2 softmax, cvt_pk pack ----------------
#define KVB 128
#define KVP 68
#define PSP 136
__global__ __launch_bounds__(512) void attn_k(
    const unsigned short* __restrict__ qkv, const int* __restrict__ x,
    unsigned short* __restrict__ out)
{
    __shared__ unsigned short KVr[KVB][KVP];      // [key][d]  17.4 KB
    __shared__ unsigned short KVt[64 * KVB];      // [d][key] swizzled, 256B rows, 16 KB
    __shared__ unsigned short Ps[8][32][PSP];     // per-wave P, 69.6 KB
    __shared__ float maskf[KVB];

    // grid (4, 16, 4) = 256 blocks; XCD-chunked bijective swizzle
    int flat = blockIdx.x + 4 * (blockIdx.y + 16 * blockIdx.z);
    flat = (flat & 7) * 32 + (flat >> 3);
    const int qt = flat & 3;
    const int hh = (flat >> 2) & 15;
    const int b  = flat >> 6;

    const int t    = threadIdx.x;      // 0..511
    const int w    = t >> 6;           // 0..7
    const int lane = t & 63;
    const int lrow = lane & 15, lgrp = lane >> 4;

    const unsigned short* qb_  = qkv + ((size_t)b * SEQ) * QKVN + hh * DHEAD;
    const unsigned short* kvb_ = qkv + ((size_t)b * SEQ) * QKVN + EDIM + hh * DHEAD;
    const int* xb = x + b * SEQ;
    const int qrow0 = qt * 256 + w * 32;

    bf16x8 qf[2][2];
    #pragma unroll
    for (int m = 0; m < 2; ++m)
        #pragma unroll
        for (int ks = 0; ks < 2; ++ks)
            qf[m][ks] = *reinterpret_cast<const bf16x8*>(
                qb_ + (size_t)(qrow0 + m * 16 + lrow) * QKVN + ks * 32 + lgrp * 8);

    f32x4 O[2][4];
    float mrun[2][4], lrun[2][4];
    #pragma unroll
    for (int m = 0; m < 2; ++m)
        #pragma unroll
        for (int i = 0; i < 4; ++i) {
            O[m][i] = (f32x4){0.f, 0.f, 0.f, 0.f};
            mrun[m][i] = -3e30f; lrun[m][i] = 0.f;
        }

    const int NKT = SEQ / KVB;   // 8
    ushort4 kvreg[4];
    int xv = 0;

    auto issueKV = [&](int kt) {
        #pragma unroll
        for (int i = 0; i < 4; ++i) {
            const int u2 = t + i * 512;
            const int kr = u2 >> 4, kc = (u2 & 15) * 4;
            kvreg[i] = *reinterpret_cast<const ushort4*>(
                &kvb_[(size_t)(kt * KVB + kr) * QKVN + kc]);
        }
        if (t < KVB) xv = xb[kt * KVB + t];
    };
    issueKV(0);

    for (int kt = 0; kt < NKT; ++kt) {
        __syncthreads();
        #pragma unroll
        for (int i = 0; i < 4; ++i) {
            const int u2 = t + i * 512;
            const int kr = u2 >> 4, kc = (u2 & 15) * 4;
            *reinterpret_cast<ushort4*>(&KVr[kr][kc]) = kvreg[i];
            const unsigned short comp[4] = {kvreg[i].x, kvreg[i].y, kvreg[i].z, kvreg[i].w};
            #pragma unroll
            for (int j = 0; j < 4; ++j) {
                const int d = kc + j;
                const int sw = (d ^ (d >> 3)) & 7;
                KVt[(d * 256 + ((kr * 2) ^ (sw << 4))) >> 1] = comp[j];
            }
        }
        if (t < KVB) maskf[t] = (xv != 0) ? 1.f : 0.f;
        if (kt + 1 < NKT) issueKV(kt + 1);
        __syncthreads();

        // QK^T: 8 n-frags of 16 keys (scores already in log2 domain via pre-scaled Q)
        f32x4 s[2][8];
        #pragma unroll
        for (int m = 0; m < 2; ++m)
            #pragma unroll
            for (int n = 0; n < 8; ++n) s[m][n] = (f32x4){0.f, 0.f, 0.f, 0.f};
        __builtin_amdgcn_s_setprio(1);
        #pragma unroll
        for (int ks = 0; ks < 2; ++ks)
            #pragma unroll
            for (int n = 0; n < 8; ++n) {
                union { bf16x8 v; ushort4 h[2]; } bb;
                bb.h[0] = *reinterpret_cast<const ushort4*>(
                    &KVr[16 * n + lrow][ks * 32 + lgrp * 8]);
                bb.h[1] = *reinterpret_cast<const ushort4*>(
                    &KVr[16 * n + lrow][ks * 32 + lgrp * 8 + 4]);
                #pragma unroll
                for (int m = 0; m < 2; ++m)
                    s[m][n] = __builtin_amdgcn_mfma_f32_16x16x32_bf16(
                        qf[m][ks], bb.v, s[m][n], 0, 0, 0);
            }
        __builtin_amdgcn_s_setprio(0);

        // mask (replacement semantics)
        #pragma unroll
        for (int n = 0; n < 8; ++n) {
            const float flag = maskf[16 * n + lrow];
            #pragma unroll
            for (int m = 0; m < 2; ++m)
                #pragma unroll
                for (int r = 0; r < 4; ++r)
                    s[m][n][r] = (flag != 0.f) ? s[m][n][r] : -1e9f;
        }

        // tile max per row + T13 defer-max (THR=11 in log2 domain)
        float tmax[2][4];
        float worst = -3e38f;
        #pragma unroll
        for (int m = 0; m < 2; ++m)
            #pragma unroll
            for (int r = 0; r < 4; ++r) {
                float v = fmaxf(fmaxf(fmaxf(s[m][0][r], s[m][1][r]),
                                      fmaxf(s[m][2][r], s[m][3][r])),
                                fmaxf(fmaxf(s[m][4][r], s[m][5][r]),
                                      fmaxf(s[m][6][r], s[m][7][r])));
                #pragma unroll
                for (int o = 1; o < 16; o <<= 1) v = fmaxf(v, __shfl_xor(v, o));
                tmax[m][r] = v;
                worst = fmaxf(worst, v - mrun[m][r]);
            }
        if (!__all(worst <= 11.f)) {
            #pragma unroll
            for (int m = 0; m < 2; ++m)
                #pragma unroll
                for (int r = 0; r < 4; ++r) {
                    const float mn = fmaxf(mrun[m][r], tmax[m][r]);
                    const float fs = exp2f(mrun[m][r] - mn);
                    mrun[m][r] = mn;
                    lrun[m][r] *= fs;
                    #pragma unroll
                    for (int df = 0; df < 4; ++df) O[m][df][r] *= fs;
                }
        }

        // P = exp2(s - m); pack pairs via v_cvt_pk_bf16_f32 (RNE, same as bit-twiddle)
        #pragma unroll
        for (int m = 0; m < 2; ++m) {
            float rsum[4] = {0.f, 0.f, 0.f, 0.f};
            #pragma unroll
            for (int n = 0; n < 8; ++n) {
                const float p0 = exp2f(s[m][n][0] - mrun[m][0]);
                const float p1 = exp2f(s[m][n][1] - mrun[m][1]);
                const float p2 = exp2f(s[m][n][2] - mrun[m][2]);
                const float p3 = exp2f(s[m][n][3] - mrun[m][3]);
                rsum[0] += p0; rsum[1] += p1; rsum[2] += p2; rsum[3] += p3;
                const unsigned pk01 = cvt_pk_bf16(p0, p1);
                const unsigned pk23 = cvt_pk_bf16(p2, p3);
                unsigned short* prow = &Ps[w][m * 16 + 4 * lgrp][16 * n + lrow];
                prow[0 * PSP] = (unsigned short)pk01;
                prow[1 * PSP] = (unsigned short)(pk01 >> 16);
                prow[2 * PSP] = (unsigned short)pk23;
                prow[3 * PSP] = (unsigned short)(pk23 >> 16);
            }
            #pragma unroll
            for (int r = 0; r < 4; ++r) {
                float v = rsum[r];
                #pragma unroll
                for (int o = 1; o < 16; o <<= 1) v += __shfl_xor(v, o);
                lrun[m][r] += v;
            }
        }

        // PV: 4 k-slices of 32 keys
        __builtin_amdgcn_s_setprio(1);
        #pragma unroll
        for (int ks2 = 0; ks2 < 4; ++ks2) {
            bf16x8 paf[2];
            #pragma unroll
            for (int m = 0; m < 2; ++m) {
                union { bf16x8 v; ushort4 h[2]; } pp;
                pp.h[0] = *reinterpret_cast<const ushort4*>(
                    &Ps[w][m * 16 + lrow][ks2 * 32 + lgrp * 8]);
                pp.h[1] = *reinterpret_cast<const ushort4*>(
                    &Ps[w][m * 16 + lrow][ks2 * 32 + lgrp * 8 + 4]);
                paf[m] = pp.v;
            }
            #pragma unroll
            for (int df = 0; df < 4; ++df) {
                const int d  = 16 * df + lrow;
                const int sw = (d ^ (d >> 3)) & 7;
                const bf16x8 bvf = *reinterpret_cast<const bf16x8*>(
                    &KVt[(d * 256 + ((ks2 * 64 + lgrp * 16) ^ (sw << 4))) >> 1]);
                #pragma unroll
                for (int m = 0; m < 2; ++m)
                    O[m][df] = __builtin_amdgcn_mfma_f32_16x16x32_bf16(
                        paf[m], bvf, O[m][df], 0, 0, 0);
            }
        }
        __builtin_amdgcn_s_setprio(0);
    }

    #pragma unroll
    for (int m = 0; m < 2; ++m)
        #pragma unroll
        for (int r = 0; r < 4; ++r) {
            const float inv = 1.f / lrun[m][r];
            const int row = qrow0 + m * 16 + 4 * lgrp + r;
            unsigned short* po = out + ((size_t)b * SEQ + row) * EDIM + hh * DHEAD;
            #pragma unroll
            for (int df = 0; df < 4; ++df)
                po[16 * df + lrow] = f32_to_bf16(O[m][df][r] * inv);
        }
}

// ---------------- driver ----------------
extern "C" void kernel_launch(void* const* d_in, const int* in_sizes, int n_in,
                              void* d_out, int out_size, void* d_ws, size_t ws_size,
                              hipStream_t stream)
{
    (void)in_sizes; (void)n_in; (void)out_size; (void)ws_size;

    const int*   x     = (const int*)  d_in[0];
    const float* wte   = (const float*)d_in[1];
    const float* wpe   = (const float*)d_in[2];
    const float* Wq    = (const float*)d_in[3];
    const float* bq    = (const float*)d_in[4];
    const float* Wkv   = (const float*)d_in[5];
    const float* bkv   = (const float*)d_in[6];
    const float* Wfc   = (const float*)d_in[7];
    const float* bfc   = (const float*)d_in[8];
    const float* Wproj = (const float*)d_in[9];
    const float* bproj = (const float*)d_in[10];
    const float* ln1g  = (const float*)d_in[11];
    const float* ln1b  = (const float*)d_in[12];
    const float* ln2g  = (const float*)d_in[13];
    const float* ln2b  = (const float*)d_in[14];
    const float* lnfg  = (const float*)d_in[15];
    const float* lnfb  = (const float*)d_in[16];

    const size_t MB = 1024 * 1024;
    char* W = (char*)d_ws;
    float*          h     = (float*)(W + 0 * MB);            // 16 MB f32
    unsigned short* att   = (unsigned short*)(W + 16 * MB);  // 8 MB bf16
    unsigned short* pb0   = (unsigned short*)(W + 24 * MB);  // 8 MB bf16 proj partial z0
    unsigned short* pb1   = (unsigned short*)(W + 32 * MB);  // 8 MB
    unsigned short* pb2   = (unsigned short*)(W + 40 * MB);  // 8 MB
    unsigned short* hb    = (unsigned short*)(W + 48 * MB);  // 8 MB
    unsigned short* qkv   = (unsigned short*)(W + 56 * MB);  // 16 MB (dead during proj)
    unsigned short* pb3   = (unsigned short*)(W + 56 * MB);  // 8 MB, aliases qkv (dead then)
    unsigned short* ub    = (unsigned short*)(W + 72 * MB);  // 8 MB
    unsigned short* tb    = (unsigned short*)(W + 80 * MB);  // 32 MB
    float*          bqkv  = (float*)(W + 112 * MB);          // 96 KB
    unsigned short* wqkvT = (unsigned short*)(W + 113 * MB); // 48 MB
    unsigned short* wfcT  = (unsigned short*)(W + 161 * MB); // 96 MB
    unsigned short* wpjT  = (unsigned short*)(W + 257 * MB); // 96 MB (end 353 MB)

    // ---- one-time prep: single launch, 64x64 tiles, 16B writes
    prep_k<<<dim3(64, 16, 37), 256, 0, stream>>>(
        Wq, Wkv, Wfc, Wproj, bq, bkv, wqkvT, wfcT, wpjT, bqkv);

    embed_k<<<NTOK, 256, 0, stream>>>(x, wte, wpe, h, hb);

    for (int l = 0; l < NLAYER; ++l) {
        // qkv GEMM; q columns pre-scaled by log2e for exp2-domain softmax
        gemm_bt_k<0, 1, 1><<<dim3(QKVN / 128, NTOK / 128), 256, 0, stream>>>(
            hb, wqkvT + (size_t)l * QKVN * EDIM, bqkv + (size_t)l * QKVN,
            qkv, nullptr, NTOK, QKVN, EDIM);

        attn_k<<<dim3(SEQ / 256, NHEAD, 4), 512, 0, stream>>>(qkv, x, att);

        ln1_k<<<NTOK, 256, 0, stream>>>(
            h, att, ln1g + l * EDIM, ln1b + l * EDIM, ub);

        gemm256_k<1, 0><<<dim3((NTOK / 256) * (4 * EDIM / 256), 1), 512, 0, stream>>>(
            ub, wfcT + (size_t)l * 4 * EDIM * EDIM, bfc + (size_t)l * 4 * EDIM,
            tb, nullptr, nullptr, nullptr, nullptr, NTOK, 4 * EDIM, EDIM);

        // proj: 8-phase 256^2 split-K=4 -> bf16 partials pb0..pb3
        gemm256_k<0, 2><<<dim3((NTOK / 256) * (EDIM / 256), 4), 512, 0, stream>>>(
            tb, wpjT + (size_t)l * 4 * EDIM * EDIM, bproj + (size_t)l * EDIM,
            nullptr, pb0, pb1, pb2, pb3, NTOK, EDIM, 4 * EDIM);

        ln2_k<<<NTOK, 256, 0, stream>>>(
            pb0, pb1, pb2, pb3, h, ln2g + l * EDIM, ln2b + l * EDIM, h, hb);
    }

    add_ln_k<1, 0><<<NTOK, 256, 0, stream>>>(
        h, lnfg, lnfb, (float*)d_out, nullptr);
}

// Round 16
// 2412.951 us; speedup vs baseline: 1.0034x; 1.0034x over previous
//
#include <hip/hip_runtime.h>

#define SEQ    1024
#define EDIM   1024
#define NHEAD  16
#define DHEAD  64
#define NLAYER 12
#define NTOK   4096   // B*S
#define QKVN   2048   // fused q|kv output width
#define LOG2E  1.44269504088896f

typedef float f32x4  __attribute__((ext_vector_type(4)));
typedef short bf16x8 __attribute__((ext_vector_type(8)));

__device__ __forceinline__ unsigned short f32_to_bf16(float f) {
    union { float f; unsigned u; } v; v.f = f;
    return (unsigned short)((v.u + 0x7fffu + ((v.u >> 16) & 1u)) >> 16);
}
__device__ __forceinline__ float bf16_to_f32(unsigned short u) {
    union { unsigned u; float f; } v; v.u = (unsigned)u << 16;
    return v.f;
}
__device__ __forceinline__ unsigned cvt_pk_bf16(float a, float b) {
    unsigned r;
    asm("v_cvt_pk_bf16_f32 %0, %1, %2" : "=v"(r) : "v"(a), "v"(b));
    return r;   // lo16 = bf16(a), hi16 = bf16(b), RNE (same as f32_to_bf16)
}

__device__ __forceinline__ float gelu_f(float x) {
    // tanh-form gelu; |err| ~3e-4 vs exact erf — below bf16 rounding here (absmax-verified)
    const float y = 0.7978845608028654f * (x + 0.044715f * x * x * x);
    const float e = __expf(-2.f * fabsf(y));
    float th = (1.f - e) / (1.f + e);
    th = (y < 0.f) ? -th : th;
    return 0.5f * x * (1.f + th);
}

__device__ __forceinline__ void gload_lds16(const unsigned short* g, unsigned short* l) {
    __builtin_amdgcn_global_load_lds((const __attribute__((address_space(1))) void*)g,
                                     (__attribute__((address_space(3))) void*)l, 16, 0, 0);
}

#define BARRIER() do { __builtin_amdgcn_s_barrier(); asm volatile("" ::: "memory"); } while (0)

// ---------------- merged one-time prep (128k x 64n tiles, 8-deep load MLP) ----------------
// grid (64, 8, 37)
// z 0..11:  Wfc layer z     (K=1024,N=4096): bx = n-tile (0..63), by = k-tile (0..7)
// z 12..23: Wproj layer z-12 (K=4096,N=1024): id = by*64+bx; n-tile = id&15, k-tile = id>>4 (0..31)
// z 24..35: Wq (id<128) / Wkv (128<=id<256), layer z-24: n-tile = id&15, k-tile = (id>>4)&7
// z 36:     bias concat (bx<12 = layer, by==0)
__device__ __forceinline__ void transpose_body128(
    const float* __restrict__ W, unsigned short* __restrict__ WT,
    int K, int N, int n0, int k0, int t, float (*tile)[65])
{
    #pragma unroll
    for (int i = 0; i < 8; ++i) {
        const int flat = t + i * 256;          // 0..2047
        const int r  = flat >> 4;              // k-row 0..127
        const int c4 = (flat & 15) * 4;        // n-col 0..60
        const float4 v = *reinterpret_cast<const float4*>(
            &W[(size_t)(k0 + r) * N + n0 + c4]);
        tile[r][c4 + 0] = v.x; tile[r][c4 + 1] = v.y;
        tile[r][c4 + 2] = v.z; tile[r][c4 + 3] = v.w;
    }
    __syncthreads();
    // write: n = (lane>>3) + 8*wave + 32*(i&1); k8 = (lane&7)*8 + 64*(i>>1)
    // banks (k8 + j + n)&31 = ((l&7)*8 + (l>>3) + const)&31 -> 2-way, free;
    // per instruction: 8 rows x 128B contiguous -> full-line HBM writes
    #pragma unroll
    for (int i = 0; i < 4; ++i) {
        const int lane6 = t & 63, wv = t >> 6;
        const int n  = (lane6 >> 3) + 8 * wv + 32 * (i & 1);
        const int k8 = (lane6 & 7) * 8 + 64 * (i >> 1);
        bf16x8 o;
        #pragma unroll
        for (int j = 0; j < 8; ++j)
            o[j] = (short)f32_to_bf16(tile[k8 + j][n]);
        *reinterpret_cast<bf16x8*>(&WT[(size_t)(n0 + n) * K + k0 + k8]) = o;
    }
}

__global__ __launch_bounds__(256) void prep_k(
    const float* __restrict__ Wq, const float* __restrict__ Wkv,
    const float* __restrict__ Wfc, const float* __restrict__ Wproj,
    const float* __restrict__ bq, const float* __restrict__ bkv,
    unsigned short* __restrict__ wqkvT, unsigned short* __restrict__ wfcT,
    unsigned short* __restrict__ wpjT, float* __restrict__ bqkv)
{
    __shared__ float tile[128][65];
    const int z = blockIdx.z;
    const int t = threadIdx.x;
    const size_t E2 = (size_t)EDIM * EDIM;       // 1M
    const size_t E8 = (size_t)4 * EDIM * EDIM;   // 4M

    if (z < 12) {
        transpose_body128(Wfc + (size_t)z * E8, wfcT + (size_t)z * E8,
                          EDIM, 4 * EDIM, blockIdx.x * 64, blockIdx.y * 128, t, tile);
    } else if (z < 24) {
        const int l = z - 12;
        const int id = blockIdx.y * 64 + blockIdx.x;     // 0..511
        transpose_body128(Wproj + (size_t)l * E8, wpjT + (size_t)l * E8,
                          4 * EDIM, EDIM, (id & 15) * 64, (id >> 4) * 128, t, tile);
    } else if (z < 36) {
        const int l = z - 24;
        const int id = blockIdx.y * 64 + blockIdx.x;     // 0..511
        if (id < 128) {
            transpose_body128(Wq + (size_t)l * E2, wqkvT + (size_t)l * QKVN * EDIM,
                              EDIM, EDIM, (id & 15) * 64, (id >> 4) * 128, t, tile);
        } else if (id < 256) {
            const int id2 = id - 128;
            transpose_body128(Wkv + (size_t)l * E2, wqkvT + (size_t)l * QKVN * EDIM + E2,
                              EDIM, EDIM, (id2 & 15) * 64, (id2 >> 4) * 128, t, tile);
        }
    } else {
        if (blockIdx.y != 0 || blockIdx.x >= NLAYER) return;
        const int l = blockIdx.x;
        #pragma unroll
        for (int i = 0; i < 4; ++i) {
            const int c = t + i * 256;
            bqkv[(size_t)l * QKVN + c]        = bq[(size_t)l * EDIM + c];
            bqkv[(size_t)l * QKVN + EDIM + c] = bkv[(size_t)l * EDIM + c];
        }
    }
}

// ---------------- embedding ----------------
__global__ __launch_bounds__(256) void embed_k(
    const int* __restrict__ x, const float* __restrict__ wte,
    const float* __restrict__ wpe, float* __restrict__ h,
    unsigned short* __restrict__ hb)
{
    const int bs  = blockIdx.x;
    const int s   = bs & (SEQ - 1);
    const int tok = x[bs];
    const int c   = threadIdx.x * 4;
    float4 a = *reinterpret_cast<const float4*>(&wte[(size_t)tok * EDIM + c]);
    const float4 p = *reinterpret_cast<const float4*>(&wpe[(size_t)s * EDIM + c]);
    a.x += p.x; a.y += p.y; a.z += p.z; a.w += p.w;
    *reinterpret_cast<float4*>(&h[(size_t)bs * EDIM + c]) = a;
    ushort4 o;
    o.x = f32_to_bf16(a.x); o.y = f32_to_bf16(a.y);
    o.z = f32_to_bf16(a.z); o.w = f32_to_bf16(a.w);
    *reinterpret_cast<ushort4*>(&hb[(size_t)bs * EDIM + c]) = o;
}

// ---------------- generic LN (final layernorm) ----------------
template<int WF32, int WBF16>
__global__ __launch_bounds__(256) void add_ln_k(
    const float* __restrict__ x1, const float* __restrict__ g,
    const float* __restrict__ b, float* __restrict__ outf,
    unsigned short* __restrict__ outb)
{
    const int row = blockIdx.x;
    const int t   = threadIdx.x;
    const int c   = t * 4;
    const size_t base = (size_t)row * EDIM + c;
    float4 a = *reinterpret_cast<const float4*>(x1 + base);
    float s  = a.x + a.y + a.z + a.w;
    float ss = a.x * a.x + a.y * a.y + a.z * a.z + a.w * a.w;
    #pragma unroll
    for (int o = 32; o > 0; o >>= 1) {
        s  += __shfl_down(s, o);
        ss += __shfl_down(ss, o);
    }
    __shared__ float rs[4], rss[4];
    const int lane = t & 63, wv = t >> 6;
    if (lane == 0) { rs[wv] = s; rss[wv] = ss; }
    __syncthreads();
    s  = rs[0] + rs[1] + rs[2] + rs[3];
    ss = rss[0] + rss[1] + rss[2] + rss[3];
    const float mean = s * (1.f / EDIM);
    const float var  = ss * (1.f / EDIM) - mean * mean;
    const float inv  = rsqrtf(var + 1e-5f);
    const float4 gv = *reinterpret_cast<const float4*>(g + c);
    const float4 bv = *reinterpret_cast<const float4*>(b + c);
    float4 y;
    y.x = (a.x - mean) * inv * gv.x + bv.x;
    y.y = (a.y - mean) * inv * gv.y + bv.y;
    y.z = (a.z - mean) * inv * gv.z + bv.z;
    y.w = (a.w - mean) * inv * gv.w + bv.w;
    if (WF32) *reinterpret_cast<float4*>(outf + base) = y;
    if (WBF16) {
        ushort4 o;
        o.x = f32_to_bf16(y.x); o.y = f32_to_bf16(y.y);
        o.z = f32_to_bf16(y.z); o.w = f32_to_bf16(y.w);
        *reinterpret_cast<ushort4*>(outb + base) = o;
    }
}

// ---------------- ln1: u = LN(h + att_bf16) -> ub bf16 ----------------
__global__ __launch_bounds__(256) void ln1_k(
    const float* __restrict__ h, const unsigned short* __restrict__ attb,
    const float* __restrict__ g, const float* __restrict__ b,
    unsigned short* __restrict__ ub)
{
    const int row = blockIdx.x;
    const int t   = threadIdx.x;
    const int c   = t * 4;
    const size_t base = (size_t)row * EDIM + c;
    float4 a = *reinterpret_cast<const float4*>(h + base);
    const ushort4 av = *reinterpret_cast<const ushort4*>(attb + base);
    a.x += bf16_to_f32(av.x); a.y += bf16_to_f32(av.y);
    a.z += bf16_to_f32(av.z); a.w += bf16_to_f32(av.w);
    float s  = a.x + a.y + a.z + a.w;
    float ss = a.x * a.x + a.y * a.y + a.z * a.z + a.w * a.w;
    #pragma unroll
    for (int o = 32; o > 0; o >>= 1) {
        s  += __shfl_down(s, o);
        ss += __shfl_down(ss, o);
    }
    __shared__ float rs[4], rss[4];
    const int lane = t & 63, wv = t >> 6;
    if (lane == 0) { rs[wv] = s; rss[wv] = ss; }
    __syncthreads();
    s  = rs[0] + rs[1] + rs[2] + rs[3];
    ss = rss[0] + rss[1] + rss[2] + rss[3];
    const float mean = s * (1.f / EDIM);
    const float var  = ss * (1.f / EDIM) - mean * mean;
    const float inv  = rsqrtf(var + 1e-5f);
    const float4 gv = *reinterpret_cast<const float4*>(g + c);
    const float4 bv = *reinterpret_cast<const float4*>(b + c);
    ushort4 o;
    o.x = f32_to_bf16((a.x - mean) * inv * gv.x + bv.x);
    o.y = f32_to_bf16((a.y - mean) * inv * gv.y + bv.y);
    o.z = f32_to_bf16((a.z - mean) * inv * gv.z + bv.z);
    o.w = f32_to_bf16((a.w - mean) * inv * gv.w + bv.w);
    *reinterpret_cast<ushort4*>(ub + base) = o;
}

// ---------------- ln2: h' = LN(p0+p1+p2+p3 + h) -> h f32 + hb bf16 ----------------
__global__ __launch_bounds__(256) void ln2_k(
    const unsigned short* __restrict__ p0, const unsigned short* __restrict__ p1,
    const unsigned short* __restrict__ p2, const unsigned short* __restrict__ p3,
    const float* __restrict__ h, const float* __restrict__ g,
    const float* __restrict__ b, float* __restrict__ hout,
    unsigned short* __restrict__ hbout)
{
    const int row = blockIdx.x;
    const int t   = threadIdx.x;
    const int c   = t * 4;
    const size_t base = (size_t)row * EDIM + c;
    float4 a = *reinterpret_cast<const float4*>(h + base);
    const ushort4 v0 = *reinterpret_cast<const ushort4*>(p0 + base);
    const ushort4 v1 = *reinterpret_cast<const ushort4*>(p1 + base);
    const ushort4 v2 = *reinterpret_cast<const ushort4*>(p2 + base);
    const ushort4 v3 = *reinterpret_cast<const ushort4*>(p3 + base);
    a.x += bf16_to_f32(v0.x) + bf16_to_f32(v1.x) + bf16_to_f32(v2.x) + bf16_to_f32(v3.x);
    a.y += bf16_to_f32(v0.y) + bf16_to_f32(v1.y) + bf16_to_f32(v2.y) + bf16_to_f32(v3.y);
    a.z += bf16_to_f32(v0.z) + bf16_to_f32(v1.z) + bf16_to_f32(v2.z) + bf16_to_f32(v3.z);
    a.w += bf16_to_f32(v0.w) + bf16_to_f32(v1.w) + bf16_to_f32(v2.w) + bf16_to_f32(v3.w);
    float s  = a.x + a.y + a.z + a.w;
    float ss = a.x * a.x + a.y * a.y + a.z * a.z + a.w * a.w;
    #pragma unroll
    for (int o = 32; o > 0; o >>= 1) {
        s  += __shfl_down(s, o);
        ss += __shfl_down(ss, o);
    }
    __shared__ float rs[4], rss[4];
    const int lane = t & 63, wv = t >> 6;
    if (lane == 0) { rs[wv] = s; rss[wv] = ss; }
    __syncthreads();
    s  = rs[0] + rs[1] + rs[2] + rs[3];
    ss = rss[0] + rss[1] + rss[2] + rss[3];
    const float mean = s * (1.f / EDIM);
    const float var  = ss * (1.f / EDIM) - mean * mean;
    const float inv  = rsqrtf(var + 1e-5f);
    const float4 gv = *reinterpret_cast<const float4*>(g + c);
    const float4 bv = *reinterpret_cast<const float4*>(b + c);
    float4 y;
    y.x = (a.x - mean) * inv * gv.x + bv.x;
    y.y = (a.y - mean) * inv * gv.y + bv.y;
    y.z = (a.z - mean) * inv * gv.z + bv.z;
    y.w = (a.w - mean) * inv * gv.w + bv.w;
    *reinterpret_cast<float4*>(hout + base) = y;
    ushort4 o;
    o.x = f32_to_bf16(y.x); o.y = f32_to_bf16(y.y);
    o.z = f32_to_bf16(y.z); o.w = f32_to_bf16(y.w);
    *reinterpret_cast<ushort4*>(hbout + base) = o;
}

// ---------------- GEMM m97 (128^2, used for qkv; QSCALE multiplies cols<EDIM by log2e) ----------------
template<int GELU, int OUTBF16, int QSCALE>
__global__ __launch_bounds__(256) void gemm_bt_k(
    const unsigned short* __restrict__ A,
    const unsigned short* __restrict__ BT,
    const float* __restrict__ bias, void* __restrict__ Cout,
    void* __restrict__ Cout2, int M, int N, int K)
{
    __shared__ unsigned short As[128 * 32];
    __shared__ unsigned short Bs[128 * 32];

    const int t    = threadIdx.x;
    const int lane = t & 63;
    const int wave = t >> 6;
    const int wr   = wave >> 1, wc = wave & 1;
    const int lrow = lane & 15, lgrp = lane >> 4;

    const int nbx = gridDim.x;
    int flat = blockIdx.y * nbx + blockIdx.x;
    const int nwg = nbx * gridDim.y;
    flat = (flat & 7) * (nwg >> 3) + (flat >> 3);
    const int row0 = (flat / nbx) * 128, col0 = (flat % nbx) * 128;

    const int kspan = K / gridDim.z;
    const int koff  = blockIdx.z * kspan;

    const int srow  = lane >> 2;
    const int skoff = (lane & 3) * 8;
    const unsigned short* aP0 = A  + (size_t)(row0 + 32 * wave + srow) * K + skoff;
    const unsigned short* aP1 = aP0 + (size_t)16 * K;
    const unsigned short* bP0 = BT + (size_t)(col0 + 32 * wave + srow) * K + skoff;
    const unsigned short* bP1 = bP0 + (size_t)16 * K;
    unsigned short* aL0 = As + wave * 1024;
    unsigned short* aL1 = As + wave * 1024 + 512;
    unsigned short* bL0 = Bs + wave * 1024;
    unsigned short* bL1 = Bs + wave * 1024 + 512;

    f32x4 acc[4][4];
    #pragma unroll
    for (int i = 0; i < 4; ++i)
        #pragma unroll
        for (int j = 0; j < 4; ++j)
            acc[i][j] = (f32x4){0.f, 0.f, 0.f, 0.f};

    for (int k0 = koff; k0 < koff + kspan; k0 += 32) {
        gload_lds16(aP0 + k0, aL0);
        gload_lds16(aP1 + k0, aL1);
        gload_lds16(bP0 + k0, bL0);
        gload_lds16(bP1 + k0, bL1);
        __syncthreads();

        bf16x8 af[4], bf[4];
        #pragma unroll
        for (int m = 0; m < 4; ++m)
            af[m] = *reinterpret_cast<const bf16x8*>(
                &As[(wr * 64 + m * 16 + lrow) * 32 + lgrp * 8]);
        #pragma unroll
        for (int n = 0; n < 4; ++n)
            bf[n] = *reinterpret_cast<const bf16x8*>(
                &Bs[(wc * 64 + n * 16 + lrow) * 32 + lgrp * 8]);

        #pragma unroll
        for (int n = 0; n < 4; ++n)
            #pragma unroll
            for (int m = 0; m < 4; ++m)
                acc[m][n] = __builtin_amdgcn_mfma_f32_16x16x32_bf16(
                    af[m], bf[n], acc[m][n], 0, 0, 0);
        __syncthreads();
    }

    const int z = blockIdx.z;
    #pragma unroll
    for (int n = 0; n < 4; ++n) {
        const int col = col0 + wc * 64 + n * 16 + lrow;
        const float bv = (z == 0) ? bias[col] : 0.f;
        const float qs = (QSCALE && col < EDIM) ? LOG2E : 1.f;
        #pragma unroll
        for (int m = 0; m < 4; ++m) {
            const int rb = row0 + wr * 64 + m * 16 + lgrp * 4;
            #pragma unroll
            for (int r = 0; r < 4; ++r) {
                float xv = acc[m][n][r] + bv;
                if (GELU) xv = gelu_f(xv);
                if (QSCALE) xv *= qs;
                if (OUTBF16) {
                    ((unsigned short*)Cout)[(size_t)(rb + r) * N + col] = f32_to_bf16(xv);
                } else {
                    float* dst = (z == 0) ? (float*)Cout : (float*)Cout2;
                    dst[(size_t)(rb + r) * N + col] = xv;
                }
            }
        }
    }
}

// ---------------- GEMM 256^2 8-phase; OUT: 0=bf16 C, 2=bf16 4-way split-K partials ----------------
template<int GELU, int OUT>
__global__ __launch_bounds__(512) void gemm256_k(
    const unsigned short* __restrict__ A,
    const unsigned short* __restrict__ BT,
    const float* __restrict__ bias, unsigned short* __restrict__ C,
    void* __restrict__ P0, void* __restrict__ P1,
    void* __restrict__ P2, void* __restrict__ P3,
    int M, int N, int K)
{
    __shared__ unsigned short sh[65536];          // A: [0,32768) B: [32768,65536)
    unsigned short* Asm = sh;
    unsigned short* Bsm = sh + 32768;

    const int tid  = threadIdx.x;
    const int lane = tid & 63;
    const int wave = tid >> 6;
    const int wm   = wave >> 2;
    const int wn   = wave & 3;
    const int lrow = lane & 15, lgrp = lane >> 4;

    const int ntc = N >> 8;
    const int nwg = gridDim.x;
    int flat = (blockIdx.x & 7) * (nwg >> 3) + (blockIdx.x >> 3);
    const int row0 = (flat / ntc) * 256;
    const int col0 = (flat % ntc) * 256;

    const int kspan = K / gridDim.y;
    const int koff  = blockIdx.y * kspan;
    const int NT    = kspan >> 6;

    f32x4 acc[8][4];
    #pragma unroll
    for (int i = 0; i < 8; ++i)
        #pragma unroll
        for (int j = 0; j < 4; ++j)
            acc[i][j] = (f32x4){0.f, 0.f, 0.f, 0.f};

    auto stage_half = [&](const unsigned short* g, unsigned short* l) {
        #pragma unroll
        for (int c = 0; c < 2; ++c) {
            const int d = (tid + c * 512) * 16;
            const int L = d ^ (((d >> 7) & 7) << 4);
            gload_lds16(g + (size_t)(L >> 7) * K + ((L & 127) >> 1), l + (d >> 1));
        }
    };
    auto stageA = [&](int buf, int kt, int h) {
        stage_half(A + (size_t)(row0 + h * 128) * K + koff + kt * 64,
                   Asm + buf * 16384 + h * 8192);
    };
    auto stageB = [&](int buf, int kt, int h) {
        stage_half(BT + (size_t)(col0 + h * 128) * K + koff + kt * 64,
                   Bsm + buf * 16384 + h * 8192);
    };

    auto rdA = [&](int buf, int p, bf16x8 (&af)[2][2]) {
        #pragma unroll
        for (int m = 0; m < 2; ++m)
            #pragma unroll
            for (int ks = 0; ks < 2; ++ks) {
                const int r  = wm * 128 + p * 32 + m * 16 + lrow;
                const int cB = (ks * 64 + lgrp * 16) ^ ((r & 7) << 4);
                af[m][ks] = *reinterpret_cast<const bf16x8*>(
                    &Asm[buf * 16384 + ((r * 128 + cB) >> 1)]);
            }
    };
    auto rdB = [&](int buf, bf16x8 (&bfr)[4][2]) {
        #pragma unroll
        for (int n = 0; n < 4; ++n)
            #pragma unroll
            for (int ks = 0; ks < 2; ++ks) {
                const int r  = wn * 64 + n * 16 + lrow;
                const int cB = (ks * 64 + lgrp * 16) ^ ((r & 7) << 4);
                bfr[n][ks] = *reinterpret_cast<const bf16x8*>(
                    &Bsm[buf * 16384 + ((r * 128 + cB) >> 1)]);
            }
    };
    auto mq = [&](int p, bf16x8 (&af)[2][2], bf16x8 (&bfr)[4][2]) {
        __builtin_amdgcn_s_setprio(1);
        #pragma unroll
        for (int ks = 0; ks < 2; ++ks)
            #pragma unroll
            for (int n = 0; n < 4; ++n)
                #pragma unroll
                for (int m = 0; m < 2; ++m)
                    acc[p * 2 + m][n] = __builtin_amdgcn_mfma_f32_16x16x32_bf16(
                        af[m][ks], bfr[n][ks], acc[p * 2 + m][n], 0, 0, 0);
        __builtin_amdgcn_s_setprio(0);
    };

    stageA(0, 0, 0); stageA(0, 0, 1);
    stageB(0, 0, 0); stageB(0, 0, 1);
    stageA(1, 1, 0); stageA(1, 1, 1);
    stageB(1, 1, 0); stageB(1, 1, 1);
    asm volatile("s_waitcnt vmcnt(8)" ::: "memory");
    BARRIER();

    for (int t = 0; t < NT; t += 2) {
        bf16x8 bfr[4][2], af[2][2];
        // ---- K-tile t (buf 0)
        rdB(0, bfr); rdA(0, 0, af);
        if (t > 0) { stageA(1, t + 1, 0); stageA(1, t + 1, 1); }
        BARRIER(); mq(0, af, bfr); BARRIER();
        rdA(0, 1, af);
        if (t + 2 < NT) stageB(0, t + 2, 0);
        BARRIER(); mq(1, af, bfr); BARRIER();
        rdA(0, 2, af);
        if (t + 2 < NT) stageB(0, t + 2, 1);
        BARRIER(); mq(2, af, bfr); BARRIER();
        rdA(0, 3, af);
        BARRIER(); mq(3, af, bfr);
        if (t + 2 < NT) { asm volatile("s_waitcnt vmcnt(4)" ::: "memory"); }
        else            { asm volatile("s_waitcnt vmcnt(0)" ::: "memory"); }
        BARRIER();
        // ---- K-tile t+1 (buf 1)
        rdB(1, bfr); rdA(1, 0, af);
        if (t + 2 < NT) stageA(0, t + 2, 0);
        BARRIER(); mq(0, af, bfr); BARRIER();
        rdA(1, 1, af);
        if (t + 2 < NT) stageA(0, t + 2, 1);
        if (t + 3 < NT) stageB(1, t + 3, 0);
        BARRIER(); mq(1, af, bfr); BARRIER();
        rdA(1, 2, af);
        if (t + 3 < NT) stageB(1, t + 3, 1);
        BARRIER(); mq(2, af, bfr); BARRIER();
        rdA(1, 3, af);
        BARRIER(); mq(3, af, bfr);
        if (t + 2 < NT) { asm volatile("s_waitcnt vmcnt(4)" ::: "memory"); }
        BARRIER();
    }

    const int z = blockIdx.y;
    #pragma unroll
    for (int n = 0; n < 4; ++n) {
        const int col = col0 + wn * 64 + n * 16 + lrow;
        const float bv = (z == 0) ? bias[col] : 0.f;
        #pragma unroll
        for (int mf = 0; mf < 8; ++mf) {
            const int rb = row0 + wm * 128 + mf * 16 + lgrp * 4;
            #pragma unroll
            for (int r = 0; r < 4; ++r) {
                float xv = acc[mf][n][r] + bv;
                if (GELU) xv = gelu_f(xv);
                if (OUT == 0) {
                    C[(size_t)(rb + r) * N + col] = f32_to_bf16(xv);
                } else {
                    unsigned short* dst = (unsigned short*)(
                        (z == 0) ? P0 : (z == 1) ? P1 : (z == 2) ? P2 : P3);
                    dst[(size_t)(rb + r) * N + col] = f32_to_bf16(xv);
                }
            }
        }
    }
}

// ---------------- flash attention: 8 waves, 256 q-rows, KVBLK=128, exp2 softmax, cvt_pk pack ----------------
#define KVB 128
#define KVP 68
#define PSP 136
__global__ __launch_bounds__(512) void attn_k(
    const unsigned short* __restrict__ qkv, const int* __restrict__ x,
    unsigned short* __restrict__ out)
{
    __shared__ unsigned short KVr[KVB][KVP];      // [key][d]  17.4 KB
    __shared__ unsigned short KVt[64 * KVB];      // [d][key] swizzled, 256B rows, 16 KB
    __shared__ unsigned short Ps[8][32][PSP];     // per-wave P, 69.6 KB
    __shared__ float maskf[KVB];

    // grid (4, 16, 4) = 256 blocks; XCD-chunked bijective swizzle
    int flat = blockIdx.x + 4 * (blockIdx.y + 16 * blockIdx.z);
    flat = (flat & 7) * 32 + (flat >> 3);
    const int qt = flat & 3;
    const int hh = (flat >> 2) & 15;
    const int b  = flat >> 6;

    const int t    = threadIdx.x;      // 0..511
    const int w    = t >> 6;           // 0..7
    const int lane = t & 63;
    const int lrow = lane & 15, lgrp = lane >> 4;

    const unsigned short* qb_  = qkv + ((size_t)b * SEQ) * QKVN + hh * DHEAD;
    const unsigned short* kvb_ = qkv + ((size_t)b * SEQ) * QKVN + EDIM + hh * DHEAD;
    const int* xb = x + b * SEQ;
    const int qrow0 = qt * 256 + w * 32;

    bf16x8 qf[2][2];
    #pragma unroll
    for (int m = 0; m < 2; ++m)
        #pragma unroll
        for (int ks = 0; ks < 2; ++ks)
            qf[m][ks] = *reinterpret_cast<const bf16x8*>(
                qb_ + (size_t)(qrow0 + m * 16 + lrow) * QKVN + ks * 32 + lgrp * 8);

    f32x4 O[2][4];
    float mrun[2][4], lrun[2][4];
    #pragma unroll
    for (int m = 0; m < 2; ++m)
        #pragma unroll
        for (int i = 0; i < 4; ++i) {
            O[m][i] = (f32x4){0.f, 0.f, 0.f, 0.f};
            mrun[m][i] = -3e30f; lrun[m][i] = 0.f;
        }

    const int NKT = SEQ / KVB;   // 8
    ushort4 kvreg[4];
    int xv = 0;

    auto issueKV = [&](int kt) {
        #pragma unroll
        for (int i = 0; i < 4; ++i) {
            const int u2 = t + i * 512;
            const int kr = u2 >> 4, kc = (u2 & 15) * 4;
            kvreg[i] = *reinterpret_cast<const ushort4*>(
                &kvb_[(size_t)(kt * KVB + kr) * QKVN + kc]);
        }
        if (t < KVB) xv = xb[kt * KVB + t];
    };
    issueKV(0);

    for (int kt = 0; kt < NKT; ++kt) {
        __syncthreads();
        #pragma unroll
        for (int i = 0; i < 4; ++i) {
            const int u2 = t + i * 512;
            const int kr = u2 >> 4, kc = (u2 & 15) * 4;
            *reinterpret_cast<ushort4*>(&KVr[kr][kc]) = kvreg[i];
            const unsigned short comp[4] = {kvreg[i].x, kvreg[i].y, kvreg[i].z, kvreg[i].w};
            #pragma unroll
            for (int j = 0; j < 4; ++j) {
                const int d = kc + j;
                const int sw = (d ^ (d >> 3)) & 7;
                KVt[(d * 256 + ((kr * 2) ^ (sw << 4))) >> 1] = comp[j];
            }
        }
        if (t < KVB) maskf[t] = (xv != 0) ? 1.f : 0.f;
        if (kt + 1 < NKT) issueKV(kt + 1);
        __syncthreads();

        // QK^T: 8 n-frags of 16 keys (scores already in log2 domain via pre-scaled Q)
        f32x4 s[2][8];
        #pragma unroll
        for (int m = 0; m < 2; ++m)
            #pragma unroll
            for (int n = 0; n < 8; ++n) s[m][n] = (f32x4){0.f, 0.f, 0.f, 0.f};
        __builtin_amdgcn_s_setprio(1);
        #pragma unroll
        for (int ks = 0; ks < 2; ++ks)
            #pragma unroll
            for (int n = 0; n < 8; ++n) {
                union { bf16x8 v; ushort4 h[2]; } bb;
                bb.h[0] = *reinterpret_cast<const ushort4*>(
                    &KVr[16 * n + lrow][ks * 32 + lgrp * 8]);
                bb.h[1] = *reinterpret_cast<const ushort4*>(
                    &KVr[16 * n + lrow][ks * 32 + lgrp * 8 + 4]);
                #pragma unroll
                for (int m = 0; m < 2; ++m)
                    s[m][n] = __builtin_amdgcn_mfma_f32_16x16x32_bf16(
                        qf[m][ks], bb.v, s[m][n], 0, 0, 0);
            }
        __builtin_amdgcn_s_setprio(0);

        // mask (replacement semantics)
        #pragma unroll
        for (int n = 0; n < 8; ++n) {
            const float flag = maskf[16 * n + lrow];
            #pragma unroll
            for (int m = 0; m < 2; ++m)
                #pragma unroll
                for (int r = 0; r < 4; ++r)
                    s[m][n][r] = (flag != 0.f) ? s[m][n][r] : -1e9f;
        }

        // tile max per row + T13 defer-max (THR=11 in log2 domain)
        float tmax[2][4];
        float worst = -3e38f;
        #pragma unroll
        for (int m = 0; m < 2; ++m)
            #pragma unroll
            for (int r = 0; r < 4; ++r) {
                float v = fmaxf(fmaxf(fmaxf(s[m][0][r], s[m][1][r]),
                                      fmaxf(s[m][2][r], s[m][3][r])),
                                fmaxf(fmaxf(s[m][4][r], s[m][5][r]),
                                      fmaxf(s[m][6][r], s[m][7][r])));
                #pragma unroll
                for (int o = 1; o < 16; o <<= 1) v = fmaxf(v, __shfl_xor(v, o));
                tmax[m][r] = v;
                worst = fmaxf(worst, v - mrun[m][r]);
            }
        if (!__all(worst <= 11.f)) {
            #pragma unroll
            for (int m = 0; m < 2; ++m)
                #pragma unroll
                for (int r = 0; r < 4; ++r) {
                    const float mn = fmaxf(mrun[m][r], tmax[m][r]);
                    const float fs = exp2f(mrun[m][r] - mn);
                    mrun[m][r] = mn;
                    lrun[m][r] *= fs;
                    #pragma unroll
                    for (int df = 0; df < 4; ++df) O[m][df][r] *= fs;
                }
        }

        // P = exp2(s - m); pack pairs via v_cvt_pk_bf16_f32 (RNE, same as bit-twiddle)
        #pragma unroll
        for (int m = 0; m < 2; ++m) {
            float rsum[4] = {0.f, 0.f, 0.f, 0.f};
            #pragma unroll
            for (int n = 0; n < 8; ++n) {
                const float p0 = exp2f(s[m][n][0] - mrun[m][0]);
                const float p1 = exp2f(s[m][n][1] - mrun[m][1]);
                const float p2 = exp2f(s[m][n][2] - mrun[m][2]);
                const float p3 = exp2f(s[m][n][3] - mrun[m][3]);
                rsum[0] += p0; rsum[1] += p1; rsum[2] += p2; rsum[3] += p3;
                const unsigned pk01 = cvt_pk_bf16(p0, p1);
                const unsigned pk23 = cvt_pk_bf16(p2, p3);
                unsigned short* prow = &Ps[w][m * 16 + 4 * lgrp][16 * n + lrow];
                prow[0 * PSP] = (unsigned short)pk01;
                prow[1 * PSP] = (unsigned short)(pk01 >> 16);
                prow[2 * PSP] = (unsigned short)pk23;
                prow[3 * PSP] = (unsigned short)(pk23 >> 16);
            }
            #pragma unroll
            for (int r = 0; r < 4; ++r) {
                float v = rsum[r];
                #pragma unroll
                for (int o = 1; o < 16; o <<= 1) v += __shfl_xor(v, o);
                lrun[m][r] += v;
            }
        }

        // PV: 4 k-slices of 32 keys
        __builtin_amdgcn_s_setprio(1);
        #pragma unroll
        for (int ks2 = 0; ks2 < 4; ++ks2) {
            bf16x8 paf[2];
            #pragma unroll
            for (int m = 0; m < 2; ++m) {
                union { bf16x8 v; ushort4 h[2]; } pp;
                pp.h[0] = *reinterpret_cast<const ushort4*>(
                    &Ps[w][m * 16 + lrow][ks2 * 32 + lgrp * 8]);
                pp.h[1] = *reinterpret_cast<const ushort4*>(
                    &Ps[w][m * 16 + lrow][ks2 * 32 + lgrp * 8 + 4]);
                paf[m] = pp.v;
            }
            #pragma unroll
            for (int df = 0; df < 4; ++df) {
                const int d  = 16 * df + lrow;
                const int sw = (d ^ (d >> 3)) & 7;
                const bf16x8 bvf = *reinterpret_cast<const bf16x8*>(
                    &KVt[(d * 256 + ((ks2 * 64 + lgrp * 16) ^ (sw << 4))) >> 1]);
                #pragma unroll
                for (int m = 0; m < 2; ++m)
                    O[m][df] = __builtin_amdgcn_mfma_f32_16x16x32_bf16(
                        paf[m], bvf, O[m][df], 0, 0, 0);
            }
        }
        __builtin_amdgcn_s_setprio(0);
    }

    #pragma unroll
    for (int m = 0; m < 2; ++m)
        #pragma unroll
        for (int r = 0; r < 4; ++r) {
            const float inv = 1.f / lrun[m][r];
            const int row = qrow0 + m * 16 + 4 * lgrp + r;
            unsigned short* po = out + ((size_t)b * SEQ + row) * EDIM + hh * DHEAD;
            #pragma unroll
            for (int df = 0; df < 4; ++df)
                po[16 * df + lrow] = f32_to_bf16(O[m][df][r] * inv);
        }
}

// ---------------- driver ----------------
extern "C" void kernel_launch(void* const* d_in, const int* in_sizes, int n_in,
                              void* d_out, int out_size, void* d_ws, size_t ws_size,
                              hipStream_t stream)
{
    (void)in_sizes; (void)n_in; (void)out_size; (void)ws_size;

    const int*   x     = (const int*)  d_in[0];
    const float* wte   = (const float*)d_in[1];
    const float* wpe   = (const float*)d_in[2];
    const float* Wq    = (const float*)d_in[3];
    const float* bq    = (const float*)d_in[4];
    const float* Wkv   = (const float*)d_in[5];
    const float* bkv   = (const float*)d_in[6];
    const float* Wfc   = (const float*)d_in[7];
    const float* bfc   = (const float*)d_in[8];
    const float* Wproj = (const float*)d_in[9];
    const float* bproj = (const float*)d_in[10];
    const float* ln1g  = (const float*)d_in[11];
    const float* ln1b  = (const float*)d_in[12];
    const float* ln2g  = (const float*)d_in[13];
    const float* ln2b  = (const float*)d_in[14];
    const float* lnfg  = (const float*)d_in[15];
    const float* lnfb  = (const float*)d_in[16];

    const size_t MB = 1024 * 1024;
    char* W = (char*)d_ws;
    float*          h     = (float*)(W + 0 * MB);            // 16 MB f32
    unsigned short* att   = (unsigned short*)(W + 16 * MB);  // 8 MB bf16
    unsigned short* pb0   = (unsigned short*)(W + 24 * MB);  // 8 MB bf16 proj partial z0
    unsigned short* pb1   = (unsigned short*)(W + 32 * MB);  // 8 MB
    unsigned short* pb2   = (unsigned short*)(W + 40 * MB);  // 8 MB
    unsigned short* hb    = (unsigned short*)(W + 48 * MB);  // 8 MB
    unsigned short* qkv   = (unsigned short*)(W + 56 * MB);  // 16 MB (dead during proj)
    unsigned short* pb3   = (unsigned short*)(W + 56 * MB);  // 8 MB, aliases qkv (dead then)
    unsigned short* ub    = (unsigned short*)(W + 72 * MB);  // 8 MB
    unsigned short* tb    = (unsigned short*)(W + 80 * MB);  // 32 MB
    float*          bqkv  = (float*)(W + 112 * MB);          // 96 KB
    unsigned short* wqkvT = (unsigned short*)(W + 113 * MB); // 48 MB
    unsigned short* wfcT  = (unsigned short*)(W + 161 * MB); // 96 MB
    unsigned short* wpjT  = (unsigned short*)(W + 257 * MB); // 96 MB (end 353 MB)

    // ---- one-time prep: single launch, 128x64 tiles, 8-deep load MLP
    prep_k<<<dim3(64, 8, 37), 256, 0, stream>>>(
        Wq, Wkv, Wfc, Wproj, bq, bkv, wqkvT, wfcT, wpjT, bqkv);

    embed_k<<<NTOK, 256, 0, stream>>>(x, wte, wpe, h, hb);

    for (int l = 0; l < NLAYER; ++l) {
        // qkv GEMM; q columns pre-scaled by log2e for exp2-domain softmax
        gemm_bt_k<0, 1, 1><<<dim3(QKVN / 128, NTOK / 128), 256, 0, stream>>>(
            hb, wqkvT + (size_t)l * QKVN * EDIM, bqkv + (size_t)l * QKVN,
            qkv, nullptr, NTOK, QKVN, EDIM);

        attn_k<<<dim3(SEQ / 256, NHEAD, 4), 512, 0, stream>>>(qkv, x, att);

        ln1_k<<<NTOK, 256, 0, stream>>>(
            h, att, ln1g + l * EDIM, ln1b + l * EDIM, ub);

        gemm256_k<1, 0><<<dim3((NTOK / 256) * (4 * EDIM / 256), 1), 512, 0, stream>>>(
            ub, wfcT + (size_t)l * 4 * EDIM * EDIM, bfc + (size_t)l * 4 * EDIM,
            tb, nullptr, nullptr, nullptr, nullptr, NTOK, 4 * EDIM, EDIM);

        // proj: 8-phase 256^2 split-K=4 -> bf16 partials pb0..pb3
        gemm256_k<0, 2><<<dim3((NTOK / 256) * (EDIM / 256), 4), 512, 0, stream>>>(
            tb, wpjT + (size_t)l * 4 * EDIM * EDIM, bproj + (size_t)l * EDIM,
            nullptr, pb0, pb1, pb2, pb3, NTOK, EDIM, 4 * EDIM);

        ln2_k<<<NTOK, 256, 0, stream>>>(
            pb0, pb1, pb2, pb3, h, ln2g + l * EDIM, ln2b + l * EDIM, h, hb);
    }

    add_ln_k<1, 0><<<NTOK, 256, 0, stream>>>(
        h, lnfg, lnfb, (float*)d_out, nullptr);
}